// Round 13
// baseline (715.144 us; speedup 1.0000x reference)
//
#include <hip/hip_runtime.h>
#include <hip/hip_bf16.h>
#include <hip/hip_fp16.h>
#include <math.h>

// Problem constants
constexpr int cB   = 2;
constexpr int cS   = 2048;
constexpr int cD   = 1024;
constexpr int cQH  = 16;
constexpr int cKVH = 4;
constexpr int cDH  = 64;
constexpr int cTOPK = 128;
constexpr int cM   = cB * cS;          // 4096 rows for all GEMMs
constexpr int cNB  = cS / 64;          // 32 j-blocks of 64
constexpr int cLSZ = 384;              // kept-list capacity (128 + tie slack)

// Attention tiling: 16 rows / 16 waves / 1024 threads, paired tiles
constexpr int cTI  = 16;               // query rows per workgroup tile
constexpr int cSTR = 258;              // staging row stride in u32 (256 + pad)

// Merged projection sizes
constexpr int cNQ  = cQH * cDH;        // 1024
constexpr int cNK  = cKVH * cDH;       // 256
constexpr int cNQKV = cNQ + 2 * cNK;   // 1536
constexpr int cVC0 = cNQ + cNK;        // 1280: first V column

typedef __attribute__((ext_vector_type(8))) short short8;
typedef __attribute__((ext_vector_type(4))) float floatx4;
typedef _Float16 half8 __attribute__((ext_vector_type(8)));

// fp32 -> bf16 round-to-nearest-even (no NaN inputs in this problem)
__device__ inline ushort f2bf(float f) {
    unsigned u = __float_as_uint(f);
    return (ushort)((u + 0x7FFFu + ((u >> 16) & 1u)) >> 16);
}

// async global -> LDS, 16B per lane (lds dest = wave-uniform base + lane*16)
__device__ __forceinline__ void glds16(const ushort* g, ushort* l) {
    __builtin_amdgcn_global_load_lds(
        (const __attribute__((address_space(1))) unsigned int*)g,
        (__attribute__((address_space(3))) unsigned int*)l, 16, 0, 0);
}

// ---------------------------------------------------------------------------
// Merged cast fp32 -> bf16 for all five GEMM inputs (dst contiguous) PLUS
// the RoPE trig table in the tail thread range (one launch total).
// Table expressions are exactly the per-element originals -> bit-identical.
// ---------------------------------------------------------------------------
constexpr int cE0 = cM * cD;                 // x end
constexpr int cE1 = cE0 + cNQ * cD;          // Wq end
constexpr int cE2 = cE1 + cNK * cD;          // Wk end
constexpr int cE3 = cE2 + cNK * cD;          // Wv end
constexpr int cE4 = cE3 + cD * cQH * cDH;    // Wo end (= total)
constexpr int cCAST4 = cE4 / 4;              // cast work-items (x4 vectors)
constexpr int cTRIG  = cS * 32;              // trig work-items

__global__ void cast_all_bf16_trig(const float* __restrict__ x,
                                   const float* __restrict__ wq,
                                   const float* __restrict__ wk,
                                   const float* __restrict__ wv,
                                   const float* __restrict__ wo,
                                   ushort* __restrict__ dst,
                                   float* __restrict__ ct,
                                   float* __restrict__ st) {
    const int idx = blockIdx.x * blockDim.x + threadIdx.x;
    if (idx < cCAST4) {
        const int i4 = idx * 4;
        const float* s;
        int off;
        if (i4 < cE0)      { s = x;  off = i4; }
        else if (i4 < cE1) { s = wq; off = i4 - cE0; }
        else if (i4 < cE2) { s = wk; off = i4 - cE1; }
        else if (i4 < cE3) { s = wv; off = i4 - cE2; }
        else               { s = wo; off = i4 - cE3; }
        const float4 v = *(const float4*)(s + off);
        ushort4 r;
        r.x = f2bf(v.x); r.y = f2bf(v.y); r.z = f2bf(v.z); r.w = f2bf(v.w);
        *(ushort4*)(dst + i4) = r;
        return;
    }
    const int t = idx - cCAST4;
    if (t >= cTRIG) return;
    const int d = t & 31;
    const int s = t >> 5;
    const float inv_freq = powf(10000.0f, -(float)d / 32.0f);
    const float ang = (float)s * inv_freq;
    ct[t] = cosf(ang);
    st[t] = sinf(ang);
}

// ---------------------------------------------------------------------------
// MFMA bf16 GEMM: C[m][n] = sum_k A[m][k] * W[n][k]  (A @ W^T), fp32 out.
// 128x128 tile, BK=32, 256 threads = 4 waves.  Staging via global_load_lds
// width=16; linear LDS with XOR granule swizzle on the read side and the
// inverse on the per-lane global source (R21; verified bit-identical).
// (Used for the output projection.)
// ---------------------------------------------------------------------------
__global__ __launch_bounds__(256) void gemm_bf16_bt(
        const ushort* __restrict__ A, const ushort* __restrict__ W,
        float* __restrict__ C, int M, int N, int K) {
    __shared__ ushort AsL[128 * 32];
    __shared__ ushort BsL[128 * 32];

    const int tid  = threadIdx.x;
    const int lane = tid & 63;
    const int w    = tid >> 6;          // 0..3
    const int wm   = (w & 1) * 64;
    const int wn   = (w >> 1) * 64;
    const int m0   = blockIdx.y * 128;
    const int n0   = blockIdx.x * 128;
    const int quad = lane >> 4;
    const int l16  = lane & 15;

    int r0, q0, r1, q1;
    {
        const int g5 = (w * 128 + lane) & 31;
        const int b4 = (g5 >> 4) & 1, b3 = (g5 >> 3) & 1, b2 = (g5 >> 2) & 1;
        const int b1 = (g5 >> 1) & 1, b0 = g5 & 1;
        r0 = ((w * 128 + lane) >> 5) * 8 + ((b4 << 2) | (b3 << 1) | (b2 ^ b4));
        q0 = ((b1 ^ b3) << 1) | (b0 ^ b2 ^ b4);
    }
    {
        const int gI = w * 128 + 64 + lane;
        const int g5 = gI & 31;
        const int b4 = (g5 >> 4) & 1, b3 = (g5 >> 3) & 1, b2 = (g5 >> 2) & 1;
        const int b1 = (g5 >> 1) & 1, b0 = g5 & 1;
        r1 = (gI >> 5) * 8 + ((b4 << 2) | (b3 << 1) | (b2 ^ b4));
        q1 = ((b1 ^ b3) << 1) | (b0 ^ b2 ^ b4);
    }
    const size_t aOff0 = (size_t)(m0 + r0) * K + q0 * 8;
    const size_t aOff1 = (size_t)(m0 + r1) * K + q1 * 8;
    const size_t bOff0 = (size_t)(n0 + r0) * K + q0 * 8;
    const size_t bOff1 = (size_t)(n0 + r1) * K + q1 * 8;
    ushort* ldsA0 = AsL + w * 1024;
    ushort* ldsA1 = AsL + w * 1024 + 512;
    ushort* ldsB0 = BsL + w * 1024;
    ushort* ldsB1 = BsL + w * 1024 + 512;

    int eA[4], eB[4];
    #pragma unroll
    for (int mi = 0; mi < 4; ++mi) {
        const int rr = wm + mi * 16 + l16;
        eA[mi] = (((rr >> 3) * 32) + ((4 * (rr & 7) + quad) ^ (rr & 7))) * 8;
    }
    #pragma unroll
    for (int ni = 0; ni < 4; ++ni) {
        const int rn = wn + ni * 16 + l16;
        eB[ni] = (((rn >> 3) * 32) + ((4 * (rn & 7) + quad) ^ (rn & 7))) * 8;
    }

    floatx4 acc[4][4];
    #pragma unroll
    for (int mi = 0; mi < 4; ++mi)
        #pragma unroll
        for (int ni = 0; ni < 4; ++ni)
            acc[mi][ni] = (floatx4){0.f, 0.f, 0.f, 0.f};

    for (int k0 = 0; k0 < K; k0 += 32) {
        glds16(A + aOff0 + k0, ldsA0);
        glds16(A + aOff1 + k0, ldsA1);
        glds16(W + bOff0 + k0, ldsB0);
        glds16(W + bOff1 + k0, ldsB1);
        __syncthreads();

        short8 af[4], bf[4];
        #pragma unroll
        for (int mi = 0; mi < 4; ++mi)
            af[mi] = *(const short8*)(AsL + eA[mi]);
        #pragma unroll
        for (int ni = 0; ni < 4; ++ni)
            bf[ni] = *(const short8*)(BsL + eB[ni]);
        #pragma unroll
        for (int mi = 0; mi < 4; ++mi)
            #pragma unroll
            for (int ni = 0; ni < 4; ++ni)
                acc[mi][ni] = __builtin_amdgcn_mfma_f32_16x16x32_bf16(
                    af[mi], bf[ni], acc[mi][ni], 0, 0, 0);
        __syncthreads();
    }

    #pragma unroll
    for (int mi = 0; mi < 4; ++mi)
        #pragma unroll
        for (int ni = 0; ni < 4; ++ni)
            #pragma unroll
            for (int r = 0; r < 4; ++r) {
                const int row = m0 + wm + mi * 16 + quad * 4 + r;
                const int col = n0 + wn + ni * 16 + l16;
                C[(size_t)row * N + col] = acc[mi][ni][r];
            }
}

// ---------------------------------------------------------------------------
// Merged QKV GEMM with FUSED RoPE (trig table) + f16-cast epilogue.
// Each wave's 64-col block aligns with one head; RoPE pair (d, d+32) lives
// in (acc[mi][ni], acc[mi][ni+2]) for ni<2.  Bit-identical (R24 verified).
// ---------------------------------------------------------------------------
__global__ __launch_bounds__(256) void gemm_qkv_rope(
        const ushort* __restrict__ A, const ushort* __restrict__ W,
        ushort* __restrict__ qff, ushort* __restrict__ kff,
        ushort* __restrict__ vff,
        const float* __restrict__ ct, const float* __restrict__ st) {
    __shared__ ushort AsL[128 * 32];
    __shared__ ushort BsL[128 * 32];

    constexpr int K = cD;
    const int tid  = threadIdx.x;
    const int lane = tid & 63;
    const int w    = tid >> 6;
    const int wm   = (w & 1) * 64;
    const int wn   = (w >> 1) * 64;
    const int m0   = blockIdx.y * 128;
    const int n0   = blockIdx.x * 128;
    const int quad = lane >> 4;
    const int l16  = lane & 15;

    int r0, q0, r1, q1;
    {
        const int g5 = (w * 128 + lane) & 31;
        const int b4 = (g5 >> 4) & 1, b3 = (g5 >> 3) & 1, b2 = (g5 >> 2) & 1;
        const int b1 = (g5 >> 1) & 1, b0 = g5 & 1;
        r0 = ((w * 128 + lane) >> 5) * 8 + ((b4 << 2) | (b3 << 1) | (b2 ^ b4));
        q0 = ((b1 ^ b3) << 1) | (b0 ^ b2 ^ b4);
    }
    {
        const int gI = w * 128 + 64 + lane;
        const int g5 = gI & 31;
        const int b4 = (g5 >> 4) & 1, b3 = (g5 >> 3) & 1, b2 = (g5 >> 2) & 1;
        const int b1 = (g5 >> 1) & 1, b0 = g5 & 1;
        r1 = (gI >> 5) * 8 + ((b4 << 2) | (b3 << 1) | (b2 ^ b4));
        q1 = ((b1 ^ b3) << 1) | (b0 ^ b2 ^ b4);
    }
    const size_t aOff0 = (size_t)(m0 + r0) * K + q0 * 8;
    const size_t aOff1 = (size_t)(m0 + r1) * K + q1 * 8;
    const size_t bOff0 = (size_t)(n0 + r0) * K + q0 * 8;
    const size_t bOff1 = (size_t)(n0 + r1) * K + q1 * 8;
    ushort* ldsA0 = AsL + w * 1024;
    ushort* ldsA1 = AsL + w * 1024 + 512;
    ushort* ldsB0 = BsL + w * 1024;
    ushort* ldsB1 = BsL + w * 1024 + 512;

    int eA[4], eB[4];
    #pragma unroll
    for (int mi = 0; mi < 4; ++mi) {
        const int rr = wm + mi * 16 + l16;
        eA[mi] = (((rr >> 3) * 32) + ((4 * (rr & 7) + quad) ^ (rr & 7))) * 8;
    }
    #pragma unroll
    for (int ni = 0; ni < 4; ++ni) {
        const int rn = wn + ni * 16 + l16;
        eB[ni] = (((rn >> 3) * 32) + ((4 * (rn & 7) + quad) ^ (rn & 7))) * 8;
    }

    floatx4 acc[4][4];
    #pragma unroll
    for (int mi = 0; mi < 4; ++mi)
        #pragma unroll
        for (int ni = 0; ni < 4; ++ni)
            acc[mi][ni] = (floatx4){0.f, 0.f, 0.f, 0.f};

    for (int k0 = 0; k0 < K; k0 += 32) {
        glds16(A + aOff0 + k0, ldsA0);
        glds16(A + aOff1 + k0, ldsA1);
        glds16(W + bOff0 + k0, ldsB0);
        glds16(W + bOff1 + k0, ldsB1);
        __syncthreads();

        short8 af[4], bf[4];
        #pragma unroll
        for (int mi = 0; mi < 4; ++mi)
            af[mi] = *(const short8*)(AsL + eA[mi]);
        #pragma unroll
        for (int ni = 0; ni < 4; ++ni)
            bf[ni] = *(const short8*)(BsL + eB[ni]);
        #pragma unroll
        for (int mi = 0; mi < 4; ++mi)
            #pragma unroll
            for (int ni = 0; ni < 4; ++ni)
                acc[mi][ni] = __builtin_amdgcn_mfma_f32_16x16x32_bf16(
                    af[mi], bf[ni], acc[mi][ni], 0, 0, 0);
        __syncthreads();
    }

    // ---- fused epilogue: this wave's 64 cols = one head block ------------
    const int colBase = n0 + wn;               // multiple of 64
    if (colBase < cNQ) {
        const int h = colBase >> 6;
        #pragma unroll
        for (int ni = 0; ni < 2; ++ni) {
            const int d = ni * 16 + l16;       // 0..31
            #pragma unroll
            for (int mi = 0; mi < 4; ++mi)
                #pragma unroll
                for (int r = 0; r < 4; ++r) {
                    const int row = m0 + wm + mi * 16 + quad * 4 + r;
                    const int s   = row & (cS - 1);
                    const float c  = ct[(s << 5) + d];
                    const float si = st[(s << 5) + d];
                    const float x1 = acc[mi][ni][r];
                    const float x2 = acc[mi][ni + 2][r];
                    const float o1 = (x1 * c - x2 * si) * 0.125f;
                    const float o2 = (x2 * c + x1 * si) * 0.125f;
                    ushort* o = qff + ((size_t)row * cQH + h) * cDH + d;
                    o[0]  = __builtin_bit_cast(ushort, (_Float16)o1);
                    o[32] = __builtin_bit_cast(ushort, (_Float16)o2);
                }
        }
    } else if (colBase < cVC0) {
        const int h = (colBase - cNQ) >> 6;
        #pragma unroll
        for (int ni = 0; ni < 2; ++ni) {
            const int d = ni * 16 + l16;
            #pragma unroll
            for (int mi = 0; mi < 4; ++mi)
                #pragma unroll
                for (int r = 0; r < 4; ++r) {
                    const int row = m0 + wm + mi * 16 + quad * 4 + r;
                    const int s   = row & (cS - 1);
                    const float c  = ct[(s << 5) + d];
                    const float si = st[(s << 5) + d];
                    const float x1 = acc[mi][ni][r];
                    const float x2 = acc[mi][ni + 2][r];
                    const float o1 = (x1 * c - x2 * si) * 1.0f;
                    const float o2 = (x2 * c + x1 * si) * 1.0f;
                    ushort* o = kff + ((size_t)row * cKVH + h) * cDH + d;
                    o[0]  = __builtin_bit_cast(ushort, (_Float16)o1);
                    o[32] = __builtin_bit_cast(ushort, (_Float16)o2);
                }
        }
    } else {
        const int h = (colBase - cVC0) >> 6;
        #pragma unroll
        for (int ni = 0; ni < 4; ++ni) {
            const int d = ni * 16 + l16;       // 0..63
            #pragma unroll
            for (int mi = 0; mi < 4; ++mi)
                #pragma unroll
                for (int r = 0; r < 4; ++r) {
                    const int row = m0 + wm + mi * 16 + quad * 4 + r;
                    vff[((size_t)row * cKVH + h) * cDH + d] =
                        __builtin_bit_cast(ushort, (_Float16)acc[mi][ni][r]);
                }
        }
    }
}

// ---------------------------------------------------------------------------
// Order-preserving float <-> uint bit maps (no NaNs here).
// ---------------------------------------------------------------------------
__device__ inline unsigned fmap(float f) {
    unsigned u = __float_as_uint(f);
    return (u & 0x80000000u) ? ~u : (u | 0x80000000u);
}
__device__ inline float funmap(unsigned u) {
    unsigned v = (u & 0x80000000u) ? (u & 0x7FFFFFFFu) : ~u;
    return __uint_as_float(v);
}

// ---------------------------------------------------------------------------
// MFMA tile attention with exact top-k threshold.  (R23 -> R25 change)
//
// R23 counters: occ 73% despite 2 blocks/CU fitting -- block work varies
// ~8:1 with `it` (chunk-rounds 1..8).  R25: WORK-PAIRED TILES.  Block p
// (p = x>>5, 0..63) processes tile itA = 127-p then tile itB = p:
// chunk-rounds = ceil((128-p)/16) + ceil((p+1)/16) = 9 for EVERY p ->
// uniform blocks, grid 2048, 4 uniform dispatch rounds.  Per-row math is
// byte-identical (same scores / selection / PV); only block->row
// assignment changes -> bit-identical output.  One extra barrier between
// tiles (staging aliases the lists).
// ---------------------------------------------------------------------------
__global__ __launch_bounds__(1024) void attn_tile_kernel(
        const ushort* __restrict__ qf, const ushort* __restrict__ kf,
        const ushort* __restrict__ vf, ushort* __restrict__ out) {
    extern __shared__ char smem[];
    unsigned* stg = (unsigned*)smem;               // [2][cTI][cSTR] staging
    unsigned* klA = (unsigned*)smem;               // aliases staging (later)
    int*      jlA = (int*)(klA + cTI * cLSZ);

    const int lane = threadIdx.x & 63;
    const int wv   = __builtin_amdgcn_readfirstlane(threadIdx.x >> 6); // 0..15

    // grid: 32 bh * 64 pairs
    const int x  = blockIdx.x;
    const int p  = x >> 5;                      // 0..63
    const int bh = x & 31;
    const int h  = bh & 15;
    const int b  = bh >> 4;
    const int kvh = h >> 2;                     // h / (QH/KVH)

    const size_t bS = (size_t)b * cS;
    const int l16   = lane & 15;
    const int quad  = lane >> 4;
    const int jperm = ((lane & 3) << 4) + (lane >> 2);   // permuted ownership
    const int vbase0 = (int)(((unsigned)bS * cKVH + kvh) * cDH);
    unsigned* kl = klA + wv * cLSZ;
    int*      jl = jlA + wv * cLSZ;

    for (int tsel = 0; tsel < 2; ++tsel) {
        // staging (phase 1) aliases the kl/jl lists still being read by the
        // previous tile's phase 2 -> barrier between tiles.
        if (tsel == 1) __syncthreads();

        const int it = tsel ? p : (127 - p);
        const int i0 = it * cTI;
        const int i  = i0 + wv;                 // this wave's query row

        // A-frags: q rows i0 + l16 (16 distinct), dims quad*8..+7 and +32
        const ushort* qp = qf + ((bS + i0 + l16) * cQH + h) * cDH + quad * 8;
        const half8 a0h = __builtin_bit_cast(half8, *(const uint4*)qp);
        const half8 a1h = __builtin_bit_cast(half8, *(const uint4*)(qp + 32));

        unsigned key[cNB];
        #pragma unroll
        for (int jb = 0; jb < cNB; ++jb) key[jb] = 0u;

        const int nk16   = it + 1;                  // 16-key blocks needed
        const int nchunk = (nk16 + 15) >> 4;        // 256-key chunks

        #pragma unroll
        for (int c = 0; c < 8; ++c) {
            if (c >= nchunk) break;             // block-uniform branch
            const int kb16 = (c << 4) + wv;     // this wave's 16-key block
            if (kb16 < nk16) {
                const ushort* kp = kf + ((bS + (kb16 << 4) + l16) * cKVH + kvh) * cDH + quad * 8;
                const uint4 b0 = *(const uint4*)kp;
                const uint4 b1 = *(const uint4*)(kp + 32);
                floatx4 acc = (floatx4){0.f, 0.f, 0.f, 0.f};
                acc = __builtin_amdgcn_mfma_f32_16x16x32_f16(
                    a0h, __builtin_bit_cast(half8, b0), acc, 0, 0, 0);
                acc = __builtin_amdgcn_mfma_f32_16x16x32_f16(
                    a1h, __builtin_bit_cast(half8, b1), acc, 0, 0, 0);
                // D: row = quad*4 + r2 (16 distinct q rows), col = l16.
                // fmap + causal mask folded into the store.
                const int jg = (kb16 << 4) + l16;       // global key idx
                unsigned* sp = stg + (c & 1) * (cTI * cSTR) + (wv << 4) + l16;
                #pragma unroll
                for (int r2 = 0; r2 < 4; ++r2) {
                    const int qrow = quad * 4 + r2;     // 0..15
                    sp[qrow * cSTR] = (jg <= i0 + qrow) ? fmap(acc[r2]) : 0u;
                }
            }
            __syncthreads();
            // gather my row's 256 chunk keys at jperm positions (2-way banks)
            {
                const unsigned* rp = stg + (c & 1) * (cTI * cSTR) + wv * cSTR;
                #pragma unroll
                for (int jj = 0; jj < 4; ++jj) {
                    const int j = (c << 8) + (jj << 6) + jperm;
                    const unsigned kr = rp[(jj << 6) + jperm];
                    key[(c << 2) + jj] = (j <= i) ? kr : 0u;
                }
            }
            // double buffer: next chunk stores to the other half; its
            // barrier orders those stores after this chunk's reads.
        }
        __syncthreads();   // staging dead; kl/jl lists may now clobber it

        // ---- Phase 2: per-row exact top-k + softmax + PV (1 row/wave) ----
        const int nb = (i >> 6) + 1;

        // row max + min over valid keys (valid keys are never 0)
        unsigned um = 0u, un = 0xFFFFFFFFu;
        #pragma unroll
        for (int jb = 0; jb < cNB; ++jb) {
            if (jb >= nb) break;
            const unsigned kk = key[jb];
            um = max(um, kk);
            un = min(un, kk ? kk : 0xFFFFFFFFu);
        }
        #pragma unroll
        for (int off = 32; off >= 1; off >>= 1) {
            um = max(um, (unsigned)__shfl_xor((int)um, off));
            un = min(un, (unsigned)__shfl_xor((int)un, off));
        }
        const float mrow = funmap(um);

        // exact 128th-largest key: bisection in [un, um] with exact-count
        // early exit; rows with i < 128 keep everything.
        unsigned ustar;
        if (i < cTOPK) {
            ustar = un;
        } else {
            unsigned lo = un, hi = um;
            while (lo < hi) {
                const unsigned d   = hi - lo;
                const unsigned mid = lo + (d >> 1) + (d & 1u);
                int cnt2 = 0;
                #pragma unroll
                for (int jb = 0; jb < cNB; ++jb) {
                    if (jb >= nb) break;
                    cnt2 += __popcll(__ballot(key[jb] >= mid));
                }
                if (cnt2 == cTOPK) {
                    unsigned mn = 0xFFFFFFFFu;
                    #pragma unroll
                    for (int jb = 0; jb < cNB; ++jb) {
                        if (jb >= nb) break;
                        const unsigned kk = key[jb];
                        mn = min(mn, (kk >= mid) ? kk : 0xFFFFFFFFu);
                    }
                    #pragma unroll
                    for (int off = 32; off >= 1; off >>= 1)
                        mn = min(mn, (unsigned)__shfl_xor((int)mn, off));
                    lo = mn;
                    break;
                }
                if (cnt2 > cTOPK) lo = mid; else hi = mid - 1u;
            }
            ustar = lo;
        }

        // ballot-prefix compaction of kept (j, key) into LDS
        const unsigned long long mlt = (1ull << lane) - 1ull;
        int base = 0;
        #pragma unroll
        for (int jb = 0; jb < cNB; ++jb) {
            if (jb >= nb) break;
            const int j = (jb << 6) + jperm;
            const bool keep = (j <= i) && (key[jb] >= ustar);
            const unsigned long long mk = __ballot(keep);
            const int pos = base + __popcll(mk & mlt);
            if (keep && pos < cLSZ) {
                kl[pos] = key[jb];
                jl[pos] = vbase0 + j * (cKVH * cDH);   // v element offset
            }
            base += __popcll(mk);
        }
        const int cnt = min(base, cLSZ);

        // weights + Z
        float zp = 0.f;
        for (int t = lane; t < cnt; t += 64) {
            const float s  = funmap(kl[t]);
            const float wt = __expf(s - mrow);
            ((float*)kl)[t] = wt;
            zp += wt;
        }
        #pragma unroll
        for (int off = 32; off >= 1; off >>= 1) zp += __shfl_xor(zp, off);
        const float invZ = 1.0f / zp;

        // PV: lane = d, f16 v, 8 independent accumulator chains, unroll 2
        float ac0 = 0.f, ac1 = 0.f, ac2 = 0.f, ac3 = 0.f;
        float ac4 = 0.f, ac5 = 0.f, ac6 = 0.f, ac7 = 0.f;
        int t = 0;
        #pragma unroll 2
        for (; t + 7 < cnt; t += 8) {
            const float wt0 = ((float*)kl)[t];
            const float wt1 = ((float*)kl)[t + 1];
            const float wt2 = ((float*)kl)[t + 2];
            const float wt3 = ((float*)kl)[t + 3];
            const float wt4 = ((float*)kl)[t + 4];
            const float wt5 = ((float*)kl)[t + 5];
            const float wt6 = ((float*)kl)[t + 6];
            const float wt7 = ((float*)kl)[t + 7];
            const int vo0 = jl[t];
            const int vo1 = jl[t + 1];
            const int vo2 = jl[t + 2];
            const int vo3 = jl[t + 3];
            const int vo4 = jl[t + 4];
            const int vo5 = jl[t + 5];
            const int vo6 = jl[t + 6];
            const int vo7 = jl[t + 7];
            ac0 += wt0 * (float)__builtin_bit_cast(_Float16, vf[vo0 + lane]);
            ac1 += wt1 * (float)__builtin_bit_cast(_Float16, vf[vo1 + lane]);
            ac2 += wt2 * (float)__builtin_bit_cast(_Float16, vf[vo2 + lane]);
            ac3 += wt3 * (float)__builtin_bit_cast(_Float16, vf[vo3 + lane]);
            ac4 += wt4 * (float)__builtin_bit_cast(_Float16, vf[vo4 + lane]);
            ac5 += wt5 * (float)__builtin_bit_cast(_Float16, vf[vo5 + lane]);
            ac6 += wt6 * (float)__builtin_bit_cast(_Float16, vf[vo6 + lane]);
            ac7 += wt7 * (float)__builtin_bit_cast(_Float16, vf[vo7 + lane]);
        }
        for (; t < cnt; ++t) {
            const float wt = ((float*)kl)[t];
            const int   vo = jl[t];
            ac0 += wt * (float)__builtin_bit_cast(_Float16, vf[vo + lane]);
        }
        const float acc = ((ac0 + ac1) + (ac2 + ac3)) + ((ac4 + ac5) + (ac6 + ac7));
        out[((bS + i) * cQH + h) * cDH + lane] = f2bf(acc * invZ);
    }
}

// ---------------------------------------------------------------------------
// Launch
// ---------------------------------------------------------------------------
extern "C" void kernel_launch(void* const* d_in, const int* in_sizes, int n_in,
                              void* d_out, int out_size, void* d_ws, size_t ws_size,
                              hipStream_t stream) {
    const float* x  = (const float*)d_in[0];
    const float* Wq = (const float*)d_in[1];
    const float* Wk = (const float*)d_in[2];
    const float* Wv = (const float*)d_in[3];
    const float* Wo = (const float*)d_in[4];
    float* out = (float*)d_out;

    // Workspace:
    //   bf16 inputs (contiguous, single merged cast): xh|Wqh|Wkh|Wvh|Woh
    //   abh : attention out (bf16); qff/kff roped f16; vff f16; trig table
    ushort* xh   = (ushort*)d_ws;
    ushort* Wqh  = xh  + (size_t)cM * cD;               // 1024 rows x 1024
    ushort* Wkh  = Wqh + (size_t)cNQ * cD;              // 256 rows
    ushort* Wvh  = Wkh + (size_t)cNK * cD;              // 256 rows (contig)
    ushort* Woh  = Wvh + (size_t)cNK * cD;              // 1024 rows
    ushort* abh  = Woh + (size_t)cD * cQH * cDH;        // 4M bf16 (attn out)
    ushort* qff  = abh + (size_t)cM * cQH * cDH;        // 4M f16 (roped q/8)
    ushort* kff  = qff + (size_t)cM * cQH * cDH;        // 1M f16 (roped k)
    ushort* vff  = kff + (size_t)cM * cKVH * cDH;       // 1M f16
    float*  ct   = (float*)(vff + (size_t)cM * cKVH * cDH);  // 64K f32
    float*  st   = ct + (size_t)cS * 32;                // 64K f32

    dim3 blk(256);

    // merged cast (all five bf16 GEMM inputs) + trig table, one launch
    cast_all_bf16_trig<<<(cCAST4 + cTRIG + 255) / 256, blk, 0, stream>>>(
        x, Wq, Wk, Wv, Wo, xh, ct, st);

    // ONE merged QKV projection with fused RoPE + f16 epilogue
    gemm_qkv_rope<<<dim3(cNQKV / 128, cM / 128), blk, 0, stream>>>(
        xh, Wqh, qff, kff, vff, ct, st);

    // Attention: work-paired tiles (uniform 9 chunk-rounds per block),
    // grid 2048, 1024 threads, 49 KB LDS -> 2 blocks/CU.
    constexpr size_t aSMEM = (size_t)cTI * cLSZ * 8;    // 49152 B
    static_assert(2 * cTI * cSTR * 4 <= (int)aSMEM, "staging must fit");
    attn_tile_kernel<<<dim3(32 * 64), dim3(1024), aSMEM, stream>>>(
        qff, kff, vff, abh);

    // Output projection (bf16 MFMA, fp32 out)
    gemm_bf16_bt<<<dim3(cD / 128, cM / 128), blk, 0, stream>>>(abh, Woh, out, cM, cD, cD);
}

// Round 14
// 501.091 us; speedup vs baseline: 1.4272x; 1.4272x over previous
//
#include <hip/hip_runtime.h>
#include <hip/hip_bf16.h>
#include <hip/hip_fp16.h>
#include <math.h>

// Problem constants
constexpr int cB   = 2;
constexpr int cS   = 2048;
constexpr int cD   = 1024;
constexpr int cQH  = 16;
constexpr int cKVH = 4;
constexpr int cDH  = 64;
constexpr int cTOPK = 128;
constexpr int cM   = cB * cS;          // 4096 rows for all GEMMs
constexpr int cNB  = cS / 64;          // 32 j-blocks of 64
constexpr int cLSZ = 384;              // kept-list capacity (128 + tie slack)

// Attention tiling (R23/R24, frozen): 16 rows / 16 waves / 1024 threads
constexpr int cTI  = 16;               // query rows per workgroup (= 16 waves)
constexpr int cSTR = 258;              // staging row stride in u32 (256 + pad)

// Merged projection sizes
constexpr int cNQ  = cQH * cDH;        // 1024
constexpr int cNK  = cKVH * cDH;       // 256
constexpr int cNQKV = cNQ + 2 * cNK;   // 1536
constexpr int cVC0 = cNQ + cNK;        // 1280: first V column

typedef __attribute__((ext_vector_type(8))) short short8;
typedef __attribute__((ext_vector_type(4))) float floatx4;
typedef _Float16 half8 __attribute__((ext_vector_type(8)));

// fp32 -> bf16 round-to-nearest-even (no NaN inputs in this problem)
__device__ inline ushort f2bf(float f) {
    unsigned u = __float_as_uint(f);
    return (ushort)((u + 0x7FFFu + ((u >> 16) & 1u)) >> 16);
}

// async global -> LDS, 16B per lane (lds dest = wave-uniform base + lane*16)
__device__ __forceinline__ void glds16(const ushort* g, ushort* l) {
    __builtin_amdgcn_global_load_lds(
        (const __attribute__((address_space(1))) unsigned int*)g,
        (__attribute__((address_space(3))) unsigned int*)l, 16, 0, 0);
}

// ---------------------------------------------------------------------------
// Merged cast fp32 -> bf16 for all five GEMM inputs (dst contiguous) PLUS
// the RoPE trig table in the tail thread range (one launch total).
// Table expressions are exactly the per-element originals -> bit-identical.
// ---------------------------------------------------------------------------
constexpr int cE0 = cM * cD;                 // x end
constexpr int cE1 = cE0 + cNQ * cD;          // Wq end
constexpr int cE2 = cE1 + cNK * cD;          // Wk end
constexpr int cE3 = cE2 + cNK * cD;          // Wv end
constexpr int cE4 = cE3 + cD * cQH * cDH;    // Wo end (= total)
constexpr int cCAST4 = cE4 / 4;              // cast work-items (x4 vectors)
constexpr int cTRIG  = cS * 32;              // trig work-items

__global__ void cast_all_bf16_trig(const float* __restrict__ x,
                                   const float* __restrict__ wq,
                                   const float* __restrict__ wk,
                                   const float* __restrict__ wv,
                                   const float* __restrict__ wo,
                                   ushort* __restrict__ dst,
                                   float* __restrict__ ct,
                                   float* __restrict__ st) {
    const int idx = blockIdx.x * blockDim.x + threadIdx.x;
    if (idx < cCAST4) {
        const int i4 = idx * 4;
        const float* s;
        int off;
        if (i4 < cE0)      { s = x;  off = i4; }
        else if (i4 < cE1) { s = wq; off = i4 - cE0; }
        else if (i4 < cE2) { s = wk; off = i4 - cE1; }
        else if (i4 < cE3) { s = wv; off = i4 - cE2; }
        else               { s = wo; off = i4 - cE3; }
        const float4 v = *(const float4*)(s + off);
        ushort4 r;
        r.x = f2bf(v.x); r.y = f2bf(v.y); r.z = f2bf(v.z); r.w = f2bf(v.w);
        *(ushort4*)(dst + i4) = r;
        return;
    }
    const int t = idx - cCAST4;
    if (t >= cTRIG) return;
    const int d = t & 31;
    const int s = t >> 5;
    const float inv_freq = powf(10000.0f, -(float)d / 32.0f);
    const float ang = (float)s * inv_freq;
    ct[t] = cosf(ang);
    st[t] = sinf(ang);
}

// ---------------------------------------------------------------------------
// MFMA bf16 GEMM: C[m][n] = sum_k A[m][k] * W[n][k]  (A @ W^T), fp32 out.
// 128x128 tile, BK=32, 256 threads = 4 waves.  Staging via global_load_lds
// width=16; linear LDS with XOR granule swizzle on the read side and the
// inverse on the per-lane global source (R21; verified bit-identical).
// (Used for the output projection.)
// ---------------------------------------------------------------------------
__global__ __launch_bounds__(256) void gemm_bf16_bt(
        const ushort* __restrict__ A, const ushort* __restrict__ W,
        float* __restrict__ C, int M, int N, int K) {
    __shared__ ushort AsL[128 * 32];
    __shared__ ushort BsL[128 * 32];

    const int tid  = threadIdx.x;
    const int lane = tid & 63;
    const int w    = tid >> 6;          // 0..3
    const int wm   = (w & 1) * 64;
    const int wn   = (w >> 1) * 64;
    const int m0   = blockIdx.y * 128;
    const int n0   = blockIdx.x * 128;
    const int quad = lane >> 4;
    const int l16  = lane & 15;

    int r0, q0, r1, q1;
    {
        const int g5 = (w * 128 + lane) & 31;
        const int b4 = (g5 >> 4) & 1, b3 = (g5 >> 3) & 1, b2 = (g5 >> 2) & 1;
        const int b1 = (g5 >> 1) & 1, b0 = g5 & 1;
        r0 = ((w * 128 + lane) >> 5) * 8 + ((b4 << 2) | (b3 << 1) | (b2 ^ b4));
        q0 = ((b1 ^ b3) << 1) | (b0 ^ b2 ^ b4);
    }
    {
        const int gI = w * 128 + 64 + lane;
        const int g5 = gI & 31;
        const int b4 = (g5 >> 4) & 1, b3 = (g5 >> 3) & 1, b2 = (g5 >> 2) & 1;
        const int b1 = (g5 >> 1) & 1, b0 = g5 & 1;
        r1 = (gI >> 5) * 8 + ((b4 << 2) | (b3 << 1) | (b2 ^ b4));
        q1 = ((b1 ^ b3) << 1) | (b0 ^ b2 ^ b4);
    }
    const size_t aOff0 = (size_t)(m0 + r0) * K + q0 * 8;
    const size_t aOff1 = (size_t)(m0 + r1) * K + q1 * 8;
    const size_t bOff0 = (size_t)(n0 + r0) * K + q0 * 8;
    const size_t bOff1 = (size_t)(n0 + r1) * K + q1 * 8;
    ushort* ldsA0 = AsL + w * 1024;
    ushort* ldsA1 = AsL + w * 1024 + 512;
    ushort* ldsB0 = BsL + w * 1024;
    ushort* ldsB1 = BsL + w * 1024 + 512;

    int eA[4], eB[4];
    #pragma unroll
    for (int mi = 0; mi < 4; ++mi) {
        const int rr = wm + mi * 16 + l16;
        eA[mi] = (((rr >> 3) * 32) + ((4 * (rr & 7) + quad) ^ (rr & 7))) * 8;
    }
    #pragma unroll
    for (int ni = 0; ni < 4; ++ni) {
        const int rn = wn + ni * 16 + l16;
        eB[ni] = (((rn >> 3) * 32) + ((4 * (rn & 7) + quad) ^ (rn & 7))) * 8;
    }

    floatx4 acc[4][4];
    #pragma unroll
    for (int mi = 0; mi < 4; ++mi)
        #pragma unroll
        for (int ni = 0; ni < 4; ++ni)
            acc[mi][ni] = (floatx4){0.f, 0.f, 0.f, 0.f};

    for (int k0 = 0; k0 < K; k0 += 32) {
        glds16(A + aOff0 + k0, ldsA0);
        glds16(A + aOff1 + k0, ldsA1);
        glds16(W + bOff0 + k0, ldsB0);
        glds16(W + bOff1 + k0, ldsB1);
        __syncthreads();

        short8 af[4], bf[4];
        #pragma unroll
        for (int mi = 0; mi < 4; ++mi)
            af[mi] = *(const short8*)(AsL + eA[mi]);
        #pragma unroll
        for (int ni = 0; ni < 4; ++ni)
            bf[ni] = *(const short8*)(BsL + eB[ni]);
        #pragma unroll
        for (int mi = 0; mi < 4; ++mi)
            #pragma unroll
            for (int ni = 0; ni < 4; ++ni)
                acc[mi][ni] = __builtin_amdgcn_mfma_f32_16x16x32_bf16(
                    af[mi], bf[ni], acc[mi][ni], 0, 0, 0);
        __syncthreads();
    }

    #pragma unroll
    for (int mi = 0; mi < 4; ++mi)
        #pragma unroll
        for (int ni = 0; ni < 4; ++ni)
            #pragma unroll
            for (int r = 0; r < 4; ++r) {
                const int row = m0 + wm + mi * 16 + quad * 4 + r;
                const int col = n0 + wn + ni * 16 + l16;
                C[(size_t)row * N + col] = acc[mi][ni][r];
            }
}

// ---------------------------------------------------------------------------
// Merged QKV GEMM with FUSED RoPE (trig table) + f16-cast epilogue.
// Each wave's 64-col block aligns with one head; RoPE pair (d, d+32) lives
// in (acc[mi][ni], acc[mi][ni+2]) for ni<2.  Bit-identical (R24 verified).
// ---------------------------------------------------------------------------
__global__ __launch_bounds__(256) void gemm_qkv_rope(
        const ushort* __restrict__ A, const ushort* __restrict__ W,
        ushort* __restrict__ qff, ushort* __restrict__ kff,
        ushort* __restrict__ vff,
        const float* __restrict__ ct, const float* __restrict__ st) {
    __shared__ ushort AsL[128 * 32];
    __shared__ ushort BsL[128 * 32];

    constexpr int K = cD;
    const int tid  = threadIdx.x;
    const int lane = tid & 63;
    const int w    = tid >> 6;
    const int wm   = (w & 1) * 64;
    const int wn   = (w >> 1) * 64;
    const int m0   = blockIdx.y * 128;
    const int n0   = blockIdx.x * 128;
    const int quad = lane >> 4;
    const int l16  = lane & 15;

    int r0, q0, r1, q1;
    {
        const int g5 = (w * 128 + lane) & 31;
        const int b4 = (g5 >> 4) & 1, b3 = (g5 >> 3) & 1, b2 = (g5 >> 2) & 1;
        const int b1 = (g5 >> 1) & 1, b0 = g5 & 1;
        r0 = ((w * 128 + lane) >> 5) * 8 + ((b4 << 2) | (b3 << 1) | (b2 ^ b4));
        q0 = ((b1 ^ b3) << 1) | (b0 ^ b2 ^ b4);
    }
    {
        const int gI = w * 128 + 64 + lane;
        const int g5 = gI & 31;
        const int b4 = (g5 >> 4) & 1, b3 = (g5 >> 3) & 1, b2 = (g5 >> 2) & 1;
        const int b1 = (g5 >> 1) & 1, b0 = g5 & 1;
        r1 = (gI >> 5) * 8 + ((b4 << 2) | (b3 << 1) | (b2 ^ b4));
        q1 = ((b1 ^ b3) << 1) | (b0 ^ b2 ^ b4);
    }
    const size_t aOff0 = (size_t)(m0 + r0) * K + q0 * 8;
    const size_t aOff1 = (size_t)(m0 + r1) * K + q1 * 8;
    const size_t bOff0 = (size_t)(n0 + r0) * K + q0 * 8;
    const size_t bOff1 = (size_t)(n0 + r1) * K + q1 * 8;
    ushort* ldsA0 = AsL + w * 1024;
    ushort* ldsA1 = AsL + w * 1024 + 512;
    ushort* ldsB0 = BsL + w * 1024;
    ushort* ldsB1 = BsL + w * 1024 + 512;

    int eA[4], eB[4];
    #pragma unroll
    for (int mi = 0; mi < 4; ++mi) {
        const int rr = wm + mi * 16 + l16;
        eA[mi] = (((rr >> 3) * 32) + ((4 * (rr & 7) + quad) ^ (rr & 7))) * 8;
    }
    #pragma unroll
    for (int ni = 0; ni < 4; ++ni) {
        const int rn = wn + ni * 16 + l16;
        eB[ni] = (((rn >> 3) * 32) + ((4 * (rn & 7) + quad) ^ (rn & 7))) * 8;
    }

    floatx4 acc[4][4];
    #pragma unroll
    for (int mi = 0; mi < 4; ++mi)
        #pragma unroll
        for (int ni = 0; ni < 4; ++ni)
            acc[mi][ni] = (floatx4){0.f, 0.f, 0.f, 0.f};

    for (int k0 = 0; k0 < K; k0 += 32) {
        glds16(A + aOff0 + k0, ldsA0);
        glds16(A + aOff1 + k0, ldsA1);
        glds16(W + bOff0 + k0, ldsB0);
        glds16(W + bOff1 + k0, ldsB1);
        __syncthreads();

        short8 af[4], bf[4];
        #pragma unroll
        for (int mi = 0; mi < 4; ++mi)
            af[mi] = *(const short8*)(AsL + eA[mi]);
        #pragma unroll
        for (int ni = 0; ni < 4; ++ni)
            bf[ni] = *(const short8*)(BsL + eB[ni]);
        #pragma unroll
        for (int mi = 0; mi < 4; ++mi)
            #pragma unroll
            for (int ni = 0; ni < 4; ++ni)
                acc[mi][ni] = __builtin_amdgcn_mfma_f32_16x16x32_bf16(
                    af[mi], bf[ni], acc[mi][ni], 0, 0, 0);
        __syncthreads();
    }

    // ---- fused epilogue: this wave's 64 cols = one head block ------------
    const int colBase = n0 + wn;               // multiple of 64
    if (colBase < cNQ) {
        const int h = colBase >> 6;
        #pragma unroll
        for (int ni = 0; ni < 2; ++ni) {
            const int d = ni * 16 + l16;       // 0..31
            #pragma unroll
            for (int mi = 0; mi < 4; ++mi)
                #pragma unroll
                for (int r = 0; r < 4; ++r) {
                    const int row = m0 + wm + mi * 16 + quad * 4 + r;
                    const int s   = row & (cS - 1);
                    const float c  = ct[(s << 5) + d];
                    const float si = st[(s << 5) + d];
                    const float x1 = acc[mi][ni][r];
                    const float x2 = acc[mi][ni + 2][r];
                    const float o1 = (x1 * c - x2 * si) * 0.125f;
                    const float o2 = (x2 * c + x1 * si) * 0.125f;
                    ushort* o = qff + ((size_t)row * cQH + h) * cDH + d;
                    o[0]  = __builtin_bit_cast(ushort, (_Float16)o1);
                    o[32] = __builtin_bit_cast(ushort, (_Float16)o2);
                }
        }
    } else if (colBase < cVC0) {
        const int h = (colBase - cNQ) >> 6;
        #pragma unroll
        for (int ni = 0; ni < 2; ++ni) {
            const int d = ni * 16 + l16;
            #pragma unroll
            for (int mi = 0; mi < 4; ++mi)
                #pragma unroll
                for (int r = 0; r < 4; ++r) {
                    const int row = m0 + wm + mi * 16 + quad * 4 + r;
                    const int s   = row & (cS - 1);
                    const float c  = ct[(s << 5) + d];
                    const float si = st[(s << 5) + d];
                    const float x1 = acc[mi][ni][r];
                    const float x2 = acc[mi][ni + 2][r];
                    const float o1 = (x1 * c - x2 * si) * 1.0f;
                    const float o2 = (x2 * c + x1 * si) * 1.0f;
                    ushort* o = kff + ((size_t)row * cKVH + h) * cDH + d;
                    o[0]  = __builtin_bit_cast(ushort, (_Float16)o1);
                    o[32] = __builtin_bit_cast(ushort, (_Float16)o2);
                }
        }
    } else {
        const int h = (colBase - cVC0) >> 6;
        #pragma unroll
        for (int ni = 0; ni < 4; ++ni) {
            const int d = ni * 16 + l16;       // 0..63
            #pragma unroll
            for (int mi = 0; mi < 4; ++mi)
                #pragma unroll
                for (int r = 0; r < 4; ++r) {
                    const int row = m0 + wm + mi * 16 + quad * 4 + r;
                    vff[((size_t)row * cKVH + h) * cDH + d] =
                        __builtin_bit_cast(ushort, (_Float16)acc[mi][ni][r]);
                }
        }
    }
}

// ---------------------------------------------------------------------------
// Order-preserving float <-> uint bit maps (no NaNs here).
// ---------------------------------------------------------------------------
__device__ inline unsigned fmap(float f) {
    unsigned u = __float_as_uint(f);
    return (u & 0x80000000u) ? ~u : (u | 0x80000000u);
}
__device__ inline float funmap(unsigned u) {
    unsigned v = (u & 0x80000000u) ? (u & 0x7FFFFFFFu) : ~u;
    return __uint_as_float(v);
}

// ---------------------------------------------------------------------------
// MFMA tile attention with exact top-k threshold.  (R23/R24, FROZEN — R25's
// work-paired tiles regressed: static balance inside barrier-synced blocks
// lost to dynamic scheduling of many small skewed blocks.  Reverted.)
// cTI=16 / 16 waves / 1024 threads; chunked MFMA scores (16 distinct q-rows
// per MFMA) -> key[32] registers via double-buffered staging; phase 2 =
// exact early-exit bisection + ballot compaction + softmax + scalar PV
// (8 chains, unroll 2).  Proven constraints: key[32] 1D fully unrolled;
// no cross-half shuffles on the critical chain; permuted key ownership.
// ---------------------------------------------------------------------------
__global__ __launch_bounds__(1024) void attn_tile_kernel(
        const ushort* __restrict__ qf, const ushort* __restrict__ kf,
        const ushort* __restrict__ vf, ushort* __restrict__ out) {
    extern __shared__ char smem[];
    unsigned* stg = (unsigned*)smem;               // [2][cTI][cSTR] staging
    unsigned* klA = (unsigned*)smem;               // aliases staging (later)
    int*      jlA = (int*)(klA + cTI * cLSZ);

    const int lane = threadIdx.x & 63;
    const int wv   = __builtin_amdgcn_readfirstlane(threadIdx.x >> 6); // 0..15

    // grid: 32 * 128 blocks; it descending so the biggest tiles start first
    const int x  = blockIdx.x;
    const int it = (cS / cTI - 1) - (x >> 5);   // 127..0
    const int bh = x & 31;
    const int h  = bh & 15;
    const int b  = bh >> 4;
    const int kvh = h >> 2;                     // h / (QH/KVH)
    const int i0  = it * cTI;

    const size_t bS = (size_t)b * cS;
    const int l16   = lane & 15;
    const int quad  = lane >> 4;
    const int jperm = ((lane & 3) << 4) + (lane >> 2);   // permuted ownership
    const int i     = i0 + wv;                  // this wave's query row

    // A-frags: q rows i0 + l16 (16 distinct), dims quad*8..+7 and +32
    // (f16, pre-scaled by 1/sqrt(DH))
    const ushort* qp = qf + ((bS + i0 + l16) * cQH + h) * cDH + quad * 8;
    const half8 a0h = __builtin_bit_cast(half8, *(const uint4*)qp);
    const half8 a1h = __builtin_bit_cast(half8, *(const uint4*)(qp + 32));

    unsigned key[cNB];
    #pragma unroll
    for (int jb = 0; jb < cNB; ++jb) key[jb] = 0u;

    const int nk16   = it + 1;                      // 16-key blocks needed
    const int nchunk = (nk16 + 15) >> 4;            // 256-key chunks

    #pragma unroll
    for (int c = 0; c < 8; ++c) {
        if (c >= nchunk) break;                 // block-uniform branch
        const int kb16 = (c << 4) + wv;         // this wave's 16-key block
        if (kb16 < nk16) {
            const ushort* kp = kf + ((bS + (kb16 << 4) + l16) * cKVH + kvh) * cDH + quad * 8;
            const uint4 b0 = *(const uint4*)kp;
            const uint4 b1 = *(const uint4*)(kp + 32);
            floatx4 acc = (floatx4){0.f, 0.f, 0.f, 0.f};
            acc = __builtin_amdgcn_mfma_f32_16x16x32_f16(
                a0h, __builtin_bit_cast(half8, b0), acc, 0, 0, 0);
            acc = __builtin_amdgcn_mfma_f32_16x16x32_f16(
                a1h, __builtin_bit_cast(half8, b1), acc, 0, 0, 0);
            // D: row = quad*4 + r2 (16 distinct q rows), col = l16.
            // fmap + causal mask folded into the store.
            const int jg = (kb16 << 4) + l16;           // global key idx
            unsigned* sp = stg + (c & 1) * (cTI * cSTR) + (wv << 4) + l16;
            #pragma unroll
            for (int r2 = 0; r2 < 4; ++r2) {
                const int qrow = quad * 4 + r2;         // 0..15
                sp[qrow * cSTR] = (jg <= i0 + qrow) ? fmap(acc[r2]) : 0u;
            }
        }
        __syncthreads();
        // gather my row's 256 chunk keys at jperm positions (2-way banks)
        {
            const unsigned* rp = stg + (c & 1) * (cTI * cSTR) + wv * cSTR;
            #pragma unroll
            for (int jj = 0; jj < 4; ++jj) {
                const int j = (c << 8) + (jj << 6) + jperm;
                const unsigned kr = rp[(jj << 6) + jperm];
                key[(c << 2) + jj] = (j <= i) ? kr : 0u;
            }
        }
        // double buffer: next chunk stores to the other half; its barrier
        // orders those stores after this chunk's reads.
    }
    __syncthreads();   // staging dead; kl/jl lists may now clobber it

    // ---- Phase 2: per-row exact top-k + softmax + PV (1 row per wave) -----
    const int nb = (i >> 6) + 1;
    unsigned* kl = klA + wv * cLSZ;
    int*      jl = jlA + wv * cLSZ;
    const int vbase0 = (int)(((unsigned)bS * cKVH + kvh) * cDH);

    // row max + min over valid keys (valid keys are never 0)
    unsigned um = 0u, un = 0xFFFFFFFFu;
    #pragma unroll
    for (int jb = 0; jb < cNB; ++jb) {
        if (jb >= nb) break;
        const unsigned kk = key[jb];
        um = max(um, kk);
        un = min(un, kk ? kk : 0xFFFFFFFFu);
    }
    #pragma unroll
    for (int off = 32; off >= 1; off >>= 1) {
        um = max(um, (unsigned)__shfl_xor((int)um, off));
        un = min(un, (unsigned)__shfl_xor((int)un, off));
    }
    const float mrow = funmap(um);

    // exact 128th-largest key: bisection in [un, um] with exact-count early
    // exit; rows with i < 128 keep everything.
    unsigned ustar;
    if (i < cTOPK) {
        ustar = un;
    } else {
        unsigned lo = un, hi = um;
        while (lo < hi) {
            const unsigned d   = hi - lo;
            const unsigned mid = lo + (d >> 1) + (d & 1u);
            int cnt2 = 0;
            #pragma unroll
            for (int jb = 0; jb < cNB; ++jb) {
                if (jb >= nb) break;
                cnt2 += __popcll(__ballot(key[jb] >= mid));
            }
            if (cnt2 == cTOPK) {
                unsigned mn = 0xFFFFFFFFu;
                #pragma unroll
                for (int jb = 0; jb < cNB; ++jb) {
                    if (jb >= nb) break;
                    const unsigned kk = key[jb];
                    mn = min(mn, (kk >= mid) ? kk : 0xFFFFFFFFu);
                }
                #pragma unroll
                for (int off = 32; off >= 1; off >>= 1)
                    mn = min(mn, (unsigned)__shfl_xor((int)mn, off));
                lo = mn;
                break;
            }
            if (cnt2 > cTOPK) lo = mid; else hi = mid - 1u;
        }
        ustar = lo;
    }

    // ballot-prefix compaction of kept (j, key) into LDS
    const unsigned long long mlt = (1ull << lane) - 1ull;
    int base = 0;
    #pragma unroll
    for (int jb = 0; jb < cNB; ++jb) {
        if (jb >= nb) break;
        const int j = (jb << 6) + jperm;
        const bool keep = (j <= i) && (key[jb] >= ustar);
        const unsigned long long mk = __ballot(keep);
        const int pos = base + __popcll(mk & mlt);
        if (keep && pos < cLSZ) {
            kl[pos] = key[jb];
            jl[pos] = vbase0 + j * (cKVH * cDH);   // v element offset
        }
        base += __popcll(mk);
    }
    const int cnt = min(base, cLSZ);

    // weights + Z
    float zp = 0.f;
    for (int t = lane; t < cnt; t += 64) {
        const float s  = funmap(kl[t]);
        const float wt = __expf(s - mrow);
        ((float*)kl)[t] = wt;
        zp += wt;
    }
    #pragma unroll
    for (int off = 32; off >= 1; off >>= 1) zp += __shfl_xor(zp, off);
    const float invZ = 1.0f / zp;

    // PV: lane = d, f16 v, 8 independent accumulator chains, unroll 2 so
    // 16 v-loads issue per body (R12-proven load overlap).
    float ac0 = 0.f, ac1 = 0.f, ac2 = 0.f, ac3 = 0.f;
    float ac4 = 0.f, ac5 = 0.f, ac6 = 0.f, ac7 = 0.f;
    int t = 0;
    #pragma unroll 2
    for (; t + 7 < cnt; t += 8) {
        const float wt0 = ((float*)kl)[t];
        const float wt1 = ((float*)kl)[t + 1];
        const float wt2 = ((float*)kl)[t + 2];
        const float wt3 = ((float*)kl)[t + 3];
        const float wt4 = ((float*)kl)[t + 4];
        const float wt5 = ((float*)kl)[t + 5];
        const float wt6 = ((float*)kl)[t + 6];
        const float wt7 = ((float*)kl)[t + 7];
        const int vo0 = jl[t];
        const int vo1 = jl[t + 1];
        const int vo2 = jl[t + 2];
        const int vo3 = jl[t + 3];
        const int vo4 = jl[t + 4];
        const int vo5 = jl[t + 5];
        const int vo6 = jl[t + 6];
        const int vo7 = jl[t + 7];
        ac0 += wt0 * (float)__builtin_bit_cast(_Float16, vf[vo0 + lane]);
        ac1 += wt1 * (float)__builtin_bit_cast(_Float16, vf[vo1 + lane]);
        ac2 += wt2 * (float)__builtin_bit_cast(_Float16, vf[vo2 + lane]);
        ac3 += wt3 * (float)__builtin_bit_cast(_Float16, vf[vo3 + lane]);
        ac4 += wt4 * (float)__builtin_bit_cast(_Float16, vf[vo4 + lane]);
        ac5 += wt5 * (float)__builtin_bit_cast(_Float16, vf[vo5 + lane]);
        ac6 += wt6 * (float)__builtin_bit_cast(_Float16, vf[vo6 + lane]);
        ac7 += wt7 * (float)__builtin_bit_cast(_Float16, vf[vo7 + lane]);
    }
    for (; t < cnt; ++t) {
        const float wt = ((float*)kl)[t];
        const int   vo = jl[t];
        ac0 += wt * (float)__builtin_bit_cast(_Float16, vf[vo + lane]);
    }
    const float acc = ((ac0 + ac1) + (ac2 + ac3)) + ((ac4 + ac5) + (ac6 + ac7));
    out[((bS + i) * cQH + h) * cDH + lane] = f2bf(acc * invZ);
}

// ---------------------------------------------------------------------------
// Launch
// ---------------------------------------------------------------------------
extern "C" void kernel_launch(void* const* d_in, const int* in_sizes, int n_in,
                              void* d_out, int out_size, void* d_ws, size_t ws_size,
                              hipStream_t stream) {
    const float* x  = (const float*)d_in[0];
    const float* Wq = (const float*)d_in[1];
    const float* Wk = (const float*)d_in[2];
    const float* Wv = (const float*)d_in[3];
    const float* Wo = (const float*)d_in[4];
    float* out = (float*)d_out;

    // Workspace:
    //   bf16 inputs (contiguous, single merged cast): xh|Wqh|Wkh|Wvh|Woh
    //   abh : attention out (bf16); qff/kff roped f16; vff f16; trig table
    ushort* xh   = (ushort*)d_ws;
    ushort* Wqh  = xh  + (size_t)cM * cD;               // 1024 rows x 1024
    ushort* Wkh  = Wqh + (size_t)cNQ * cD;              // 256 rows
    ushort* Wvh  = Wkh + (size_t)cNK * cD;              // 256 rows (contig)
    ushort* Woh  = Wvh + (size_t)cNK * cD;              // 1024 rows
    ushort* abh  = Woh + (size_t)cD * cQH * cDH;        // 4M bf16 (attn out)
    ushort* qff  = abh + (size_t)cM * cQH * cDH;        // 4M f16 (roped q/8)
    ushort* kff  = qff + (size_t)cM * cQH * cDH;        // 1M f16 (roped k)
    ushort* vff  = kff + (size_t)cM * cKVH * cDH;       // 1M f16
    float*  ct   = (float*)(vff + (size_t)cM * cKVH * cDH);  // 64K f32
    float*  st   = ct + (size_t)cS * 32;                // 64K f32

    dim3 blk(256);

    // merged cast (all five bf16 GEMM inputs) + trig table, one launch
    cast_all_bf16_trig<<<(cCAST4 + cTRIG + 255) / 256, blk, 0, stream>>>(
        x, Wq, Wk, Wv, Wo, xh, ct, st);

    // ONE merged QKV projection with fused RoPE + f16 epilogue
    gemm_qkv_rope<<<dim3(cNQKV / 128, cM / 128), blk, 0, stream>>>(
        xh, Wqh, qff, kff, vff, ct, st);

    // Attention: cTI=16 / 1024 threads / 49 KB LDS (staging 33 KB aliases
    // the kl/jl lists) -> 2 blocks/CU; grid 4096, it descending (dynamic
    // load balance across skewed blocks).
    constexpr size_t aSMEM = (size_t)cTI * cLSZ * 8;    // 49152 B
    static_assert(2 * cTI * cSTR * 4 <= (int)aSMEM, "staging must fit");
    attn_tile_kernel<<<dim3(32 * (cS / cTI)), dim3(1024), aSMEM, stream>>>(
        qff, kff, vff, abh);

    // Output projection (bf16 MFMA, fp32 out)
    gemm_bf16_bt<<<dim3(cD / 128, cM / 128), blk, 0, stream>>>(abh, Woh, out, cM, cD, cD);
}

// Round 15
// 493.427 us; speedup vs baseline: 1.4493x; 1.0155x over previous
//
#include <hip/hip_runtime.h>
#include <hip/hip_bf16.h>
#include <hip/hip_fp16.h>
#include <math.h>

// Problem constants
constexpr int cB   = 2;
constexpr int cS   = 2048;
constexpr int cD   = 1024;
constexpr int cQH  = 16;
constexpr int cKVH = 4;
constexpr int cDH  = 64;
constexpr int cTOPK = 128;
constexpr int cM   = cB * cS;          // 4096 rows for all GEMMs
constexpr int cNB  = cS / 64;          // 32 j-blocks of 64
constexpr int cLSZ = 384;              // kept-list capacity (128 + tie slack)

// Attention tiling: 16 rows / 16 waves / 1024 threads; 512-key chunks (R27)
constexpr int cTI  = 16;               // query rows per workgroup (= 16 waves)
constexpr int cSTR = 516;              // staging row stride in u32 (512 + pad)

// Merged projection sizes
constexpr int cNQ  = cQH * cDH;        // 1024
constexpr int cNK  = cKVH * cDH;       // 256
constexpr int cNQKV = cNQ + 2 * cNK;   // 1536
constexpr int cVC0 = cNQ + cNK;        // 1280: first V column

typedef __attribute__((ext_vector_type(8))) short short8;
typedef __attribute__((ext_vector_type(4))) float floatx4;
typedef _Float16 half8 __attribute__((ext_vector_type(8)));

// fp32 -> bf16 round-to-nearest-even (no NaN inputs in this problem)
__device__ inline ushort f2bf(float f) {
    unsigned u = __float_as_uint(f);
    return (ushort)((u + 0x7FFFu + ((u >> 16) & 1u)) >> 16);
}

// async global -> LDS, 16B per lane (lds dest = wave-uniform base + lane*16)
__device__ __forceinline__ void glds16(const ushort* g, ushort* l) {
    __builtin_amdgcn_global_load_lds(
        (const __attribute__((address_space(1))) unsigned int*)g,
        (__attribute__((address_space(3))) unsigned int*)l, 16, 0, 0);
}

// ---------------------------------------------------------------------------
// Merged cast fp32 -> bf16 for all five GEMM inputs (dst contiguous) PLUS
// the RoPE trig table in the tail thread range (one launch total).
// Table expressions are exactly the per-element originals -> bit-identical.
// ---------------------------------------------------------------------------
constexpr int cE0 = cM * cD;                 // x end
constexpr int cE1 = cE0 + cNQ * cD;          // Wq end
constexpr int cE2 = cE1 + cNK * cD;          // Wk end
constexpr int cE3 = cE2 + cNK * cD;          // Wv end
constexpr int cE4 = cE3 + cD * cQH * cDH;    // Wo end (= total)
constexpr int cCAST4 = cE4 / 4;              // cast work-items (x4 vectors)
constexpr int cTRIG  = cS * 32;              // trig work-items

__global__ void cast_all_bf16_trig(const float* __restrict__ x,
                                   const float* __restrict__ wq,
                                   const float* __restrict__ wk,
                                   const float* __restrict__ wv,
                                   const float* __restrict__ wo,
                                   ushort* __restrict__ dst,
                                   float* __restrict__ ct,
                                   float* __restrict__ st) {
    const int idx = blockIdx.x * blockDim.x + threadIdx.x;
    if (idx < cCAST4) {
        const int i4 = idx * 4;
        const float* s;
        int off;
        if (i4 < cE0)      { s = x;  off = i4; }
        else if (i4 < cE1) { s = wq; off = i4 - cE0; }
        else if (i4 < cE2) { s = wk; off = i4 - cE1; }
        else if (i4 < cE3) { s = wv; off = i4 - cE2; }
        else               { s = wo; off = i4 - cE3; }
        const float4 v = *(const float4*)(s + off);
        ushort4 r;
        r.x = f2bf(v.x); r.y = f2bf(v.y); r.z = f2bf(v.z); r.w = f2bf(v.w);
        *(ushort4*)(dst + i4) = r;
        return;
    }
    const int t = idx - cCAST4;
    if (t >= cTRIG) return;
    const int d = t & 31;
    const int s = t >> 5;
    const float inv_freq = powf(10000.0f, -(float)d / 32.0f);
    const float ang = (float)s * inv_freq;
    ct[t] = cosf(ang);
    st[t] = sinf(ang);
}

// ---------------------------------------------------------------------------
// MFMA bf16 GEMM: C[m][n] = sum_k A[m][k] * W[n][k]  (A @ W^T), fp32 out.
// 128x128 tile, BK=32, 256 threads = 4 waves.  Staging via global_load_lds
// width=16; linear LDS with XOR granule swizzle on the read side and the
// inverse on the per-lane global source (R21; verified bit-identical).
// (Used for the output projection.)
// ---------------------------------------------------------------------------
__global__ __launch_bounds__(256) void gemm_bf16_bt(
        const ushort* __restrict__ A, const ushort* __restrict__ W,
        float* __restrict__ C, int M, int N, int K) {
    __shared__ ushort AsL[128 * 32];
    __shared__ ushort BsL[128 * 32];

    const int tid  = threadIdx.x;
    const int lane = tid & 63;
    const int w    = tid >> 6;          // 0..3
    const int wm   = (w & 1) * 64;
    const int wn   = (w >> 1) * 64;
    const int m0   = blockIdx.y * 128;
    const int n0   = blockIdx.x * 128;
    const int quad = lane >> 4;
    const int l16  = lane & 15;

    int r0, q0, r1, q1;
    {
        const int g5 = (w * 128 + lane) & 31;
        const int b4 = (g5 >> 4) & 1, b3 = (g5 >> 3) & 1, b2 = (g5 >> 2) & 1;
        const int b1 = (g5 >> 1) & 1, b0 = g5 & 1;
        r0 = ((w * 128 + lane) >> 5) * 8 + ((b4 << 2) | (b3 << 1) | (b2 ^ b4));
        q0 = ((b1 ^ b3) << 1) | (b0 ^ b2 ^ b4);
    }
    {
        const int gI = w * 128 + 64 + lane;
        const int g5 = gI & 31;
        const int b4 = (g5 >> 4) & 1, b3 = (g5 >> 3) & 1, b2 = (g5 >> 2) & 1;
        const int b1 = (g5 >> 1) & 1, b0 = g5 & 1;
        r1 = (gI >> 5) * 8 + ((b4 << 2) | (b3 << 1) | (b2 ^ b4));
        q1 = ((b1 ^ b3) << 1) | (b0 ^ b2 ^ b4);
    }
    const size_t aOff0 = (size_t)(m0 + r0) * K + q0 * 8;
    const size_t aOff1 = (size_t)(m0 + r1) * K + q1 * 8;
    const size_t bOff0 = (size_t)(n0 + r0) * K + q0 * 8;
    const size_t bOff1 = (size_t)(n0 + r1) * K + q1 * 8;
    ushort* ldsA0 = AsL + w * 1024;
    ushort* ldsA1 = AsL + w * 1024 + 512;
    ushort* ldsB0 = BsL + w * 1024;
    ushort* ldsB1 = BsL + w * 1024 + 512;

    int eA[4], eB[4];
    #pragma unroll
    for (int mi = 0; mi < 4; ++mi) {
        const int rr = wm + mi * 16 + l16;
        eA[mi] = (((rr >> 3) * 32) + ((4 * (rr & 7) + quad) ^ (rr & 7))) * 8;
    }
    #pragma unroll
    for (int ni = 0; ni < 4; ++ni) {
        const int rn = wn + ni * 16 + l16;
        eB[ni] = (((rn >> 3) * 32) + ((4 * (rn & 7) + quad) ^ (rn & 7))) * 8;
    }

    floatx4 acc[4][4];
    #pragma unroll
    for (int mi = 0; mi < 4; ++mi)
        #pragma unroll
        for (int ni = 0; ni < 4; ++ni)
            acc[mi][ni] = (floatx4){0.f, 0.f, 0.f, 0.f};

    for (int k0 = 0; k0 < K; k0 += 32) {
        glds16(A + aOff0 + k0, ldsA0);
        glds16(A + aOff1 + k0, ldsA1);
        glds16(W + bOff0 + k0, ldsB0);
        glds16(W + bOff1 + k0, ldsB1);
        __syncthreads();

        short8 af[4], bf[4];
        #pragma unroll
        for (int mi = 0; mi < 4; ++mi)
            af[mi] = *(const short8*)(AsL + eA[mi]);
        #pragma unroll
        for (int ni = 0; ni < 4; ++ni)
            bf[ni] = *(const short8*)(BsL + eB[ni]);
        #pragma unroll
        for (int mi = 0; mi < 4; ++mi)
            #pragma unroll
            for (int ni = 0; ni < 4; ++ni)
                acc[mi][ni] = __builtin_amdgcn_mfma_f32_16x16x32_bf16(
                    af[mi], bf[ni], acc[mi][ni], 0, 0, 0);
        __syncthreads();
    }

    #pragma unroll
    for (int mi = 0; mi < 4; ++mi)
        #pragma unroll
        for (int ni = 0; ni < 4; ++ni)
            #pragma unroll
            for (int r = 0; r < 4; ++r) {
                const int row = m0 + wm + mi * 16 + quad * 4 + r;
                const int col = n0 + wn + ni * 16 + l16;
                C[(size_t)row * N + col] = acc[mi][ni][r];
            }
}

// ---------------------------------------------------------------------------
// Merged QKV GEMM with FUSED RoPE (trig table) + f16-cast epilogue.
// Each wave's 64-col block aligns with one head; RoPE pair (d, d+32) lives
// in (acc[mi][ni], acc[mi][ni+2]) for ni<2.  Bit-identical (R24 verified).
// ---------------------------------------------------------------------------
__global__ __launch_bounds__(256) void gemm_qkv_rope(
        const ushort* __restrict__ A, const ushort* __restrict__ W,
        ushort* __restrict__ qff, ushort* __restrict__ kff,
        ushort* __restrict__ vff,
        const float* __restrict__ ct, const float* __restrict__ st) {
    __shared__ ushort AsL[128 * 32];
    __shared__ ushort BsL[128 * 32];

    constexpr int K = cD;
    const int tid  = threadIdx.x;
    const int lane = tid & 63;
    const int w    = tid >> 6;
    const int wm   = (w & 1) * 64;
    const int wn   = (w >> 1) * 64;
    const int m0   = blockIdx.y * 128;
    const int n0   = blockIdx.x * 128;
    const int quad = lane >> 4;
    const int l16  = lane & 15;

    int r0, q0, r1, q1;
    {
        const int g5 = (w * 128 + lane) & 31;
        const int b4 = (g5 >> 4) & 1, b3 = (g5 >> 3) & 1, b2 = (g5 >> 2) & 1;
        const int b1 = (g5 >> 1) & 1, b0 = g5 & 1;
        r0 = ((w * 128 + lane) >> 5) * 8 + ((b4 << 2) | (b3 << 1) | (b2 ^ b4));
        q0 = ((b1 ^ b3) << 1) | (b0 ^ b2 ^ b4);
    }
    {
        const int gI = w * 128 + 64 + lane;
        const int g5 = gI & 31;
        const int b4 = (g5 >> 4) & 1, b3 = (g5 >> 3) & 1, b2 = (g5 >> 2) & 1;
        const int b1 = (g5 >> 1) & 1, b0 = g5 & 1;
        r1 = (gI >> 5) * 8 + ((b4 << 2) | (b3 << 1) | (b2 ^ b4));
        q1 = ((b1 ^ b3) << 1) | (b0 ^ b2 ^ b4);
    }
    const size_t aOff0 = (size_t)(m0 + r0) * K + q0 * 8;
    const size_t aOff1 = (size_t)(m0 + r1) * K + q1 * 8;
    const size_t bOff0 = (size_t)(n0 + r0) * K + q0 * 8;
    const size_t bOff1 = (size_t)(n0 + r1) * K + q1 * 8;
    ushort* ldsA0 = AsL + w * 1024;
    ushort* ldsA1 = AsL + w * 1024 + 512;
    ushort* ldsB0 = BsL + w * 1024;
    ushort* ldsB1 = BsL + w * 1024 + 512;

    int eA[4], eB[4];
    #pragma unroll
    for (int mi = 0; mi < 4; ++mi) {
        const int rr = wm + mi * 16 + l16;
        eA[mi] = (((rr >> 3) * 32) + ((4 * (rr & 7) + quad) ^ (rr & 7))) * 8;
    }
    #pragma unroll
    for (int ni = 0; ni < 4; ++ni) {
        const int rn = wn + ni * 16 + l16;
        eB[ni] = (((rn >> 3) * 32) + ((4 * (rn & 7) + quad) ^ (rn & 7))) * 8;
    }

    floatx4 acc[4][4];
    #pragma unroll
    for (int mi = 0; mi < 4; ++mi)
        #pragma unroll
        for (int ni = 0; ni < 4; ++ni)
            acc[mi][ni] = (floatx4){0.f, 0.f, 0.f, 0.f};

    for (int k0 = 0; k0 < K; k0 += 32) {
        glds16(A + aOff0 + k0, ldsA0);
        glds16(A + aOff1 + k0, ldsA1);
        glds16(W + bOff0 + k0, ldsB0);
        glds16(W + bOff1 + k0, ldsB1);
        __syncthreads();

        short8 af[4], bf[4];
        #pragma unroll
        for (int mi = 0; mi < 4; ++mi)
            af[mi] = *(const short8*)(AsL + eA[mi]);
        #pragma unroll
        for (int ni = 0; ni < 4; ++ni)
            bf[ni] = *(const short8*)(BsL + eB[ni]);
        #pragma unroll
        for (int mi = 0; mi < 4; ++mi)
            #pragma unroll
            for (int ni = 0; ni < 4; ++ni)
                acc[mi][ni] = __builtin_amdgcn_mfma_f32_16x16x32_bf16(
                    af[mi], bf[ni], acc[mi][ni], 0, 0, 0);
        __syncthreads();
    }

    // ---- fused epilogue: this wave's 64 cols = one head block ------------
    const int colBase = n0 + wn;               // multiple of 64
    if (colBase < cNQ) {
        const int h = colBase >> 6;
        #pragma unroll
        for (int ni = 0; ni < 2; ++ni) {
            const int d = ni * 16 + l16;       // 0..31
            #pragma unroll
            for (int mi = 0; mi < 4; ++mi)
                #pragma unroll
                for (int r = 0; r < 4; ++r) {
                    const int row = m0 + wm + mi * 16 + quad * 4 + r;
                    const int s   = row & (cS - 1);
                    const float c  = ct[(s << 5) + d];
                    const float si = st[(s << 5) + d];
                    const float x1 = acc[mi][ni][r];
                    const float x2 = acc[mi][ni + 2][r];
                    const float o1 = (x1 * c - x2 * si) * 0.125f;
                    const float o2 = (x2 * c + x1 * si) * 0.125f;
                    ushort* o = qff + ((size_t)row * cQH + h) * cDH + d;
                    o[0]  = __builtin_bit_cast(ushort, (_Float16)o1);
                    o[32] = __builtin_bit_cast(ushort, (_Float16)o2);
                }
        }
    } else if (colBase < cVC0) {
        const int h = (colBase - cNQ) >> 6;
        #pragma unroll
        for (int ni = 0; ni < 2; ++ni) {
            const int d = ni * 16 + l16;
            #pragma unroll
            for (int mi = 0; mi < 4; ++mi)
                #pragma unroll
                for (int r = 0; r < 4; ++r) {
                    const int row = m0 + wm + mi * 16 + quad * 4 + r;
                    const int s   = row & (cS - 1);
                    const float c  = ct[(s << 5) + d];
                    const float si = st[(s << 5) + d];
                    const float x1 = acc[mi][ni][r];
                    const float x2 = acc[mi][ni + 2][r];
                    const float o1 = (x1 * c - x2 * si) * 1.0f;
                    const float o2 = (x2 * c + x1 * si) * 1.0f;
                    ushort* o = kff + ((size_t)row * cKVH + h) * cDH + d;
                    o[0]  = __builtin_bit_cast(ushort, (_Float16)o1);
                    o[32] = __builtin_bit_cast(ushort, (_Float16)o2);
                }
        }
    } else {
        const int h = (colBase - cVC0) >> 6;
        #pragma unroll
        for (int ni = 0; ni < 4; ++ni) {
            const int d = ni * 16 + l16;       // 0..63
            #pragma unroll
            for (int mi = 0; mi < 4; ++mi)
                #pragma unroll
                for (int r = 0; r < 4; ++r) {
                    const int row = m0 + wm + mi * 16 + quad * 4 + r;
                    vff[((size_t)row * cKVH + h) * cDH + d] =
                        __builtin_bit_cast(ushort, (_Float16)acc[mi][ni][r]);
                }
        }
    }
}

// ---------------------------------------------------------------------------
// Order-preserving float <-> uint bit maps (no NaNs here).
// ---------------------------------------------------------------------------
__device__ inline unsigned fmap(float f) {
    unsigned u = __float_as_uint(f);
    return (u & 0x80000000u) ? ~u : (u | 0x80000000u);
}
__device__ inline float funmap(unsigned u) {
    unsigned v = (u & 0x80000000u) ? (u & 0x7FFFFFFFu) : ~u;
    return __uint_as_float(v);
}

// ---------------------------------------------------------------------------
// MFMA tile attention with exact top-k threshold.  (R26 -> R27 change)
//
// R27: 512-KEY CHUNKS.  Phase 1's barrier count halves (8 -> 4 max rounds;
// 4.5 -> 2.3 avg): per chunk each wave computes TWO 16-key MFMA blocks
// (kbA = c*32+wv, kbB = c*32+16+wv) before the single barrier, doubling
// the independent loads/MFMAs in flight per drain.  Staging [2][16][516]
// u32 = 66 KB; kl/jl lists (49 KB) alias it; 2 blocks/CU still fit
// (132 <= 160 KB) and the 32-wave/CU cap is unchanged.  All math
// bit-identical to R26 (same scores, same gather values, same phase 2).
// ---------------------------------------------------------------------------
__global__ __launch_bounds__(1024) void attn_tile_kernel(
        const ushort* __restrict__ qf, const ushort* __restrict__ kf,
        const ushort* __restrict__ vf, ushort* __restrict__ out) {
    extern __shared__ char smem[];
    unsigned* stg = (unsigned*)smem;               // [2][cTI][cSTR] staging
    unsigned* klA = (unsigned*)smem;               // aliases staging (later)
    int*      jlA = (int*)(klA + cTI * cLSZ);

    const int lane = threadIdx.x & 63;
    const int wv   = __builtin_amdgcn_readfirstlane(threadIdx.x >> 6); // 0..15

    // grid: 32 * 128 blocks; it descending so the biggest tiles start first
    const int x  = blockIdx.x;
    const int it = (cS / cTI - 1) - (x >> 5);   // 127..0
    const int bh = x & 31;
    const int h  = bh & 15;
    const int b  = bh >> 4;
    const int kvh = h >> 2;                     // h / (QH/KVH)
    const int i0  = it * cTI;

    const size_t bS = (size_t)b * cS;
    const int l16   = lane & 15;
    const int quad  = lane >> 4;
    const int jperm = ((lane & 3) << 4) + (lane >> 2);   // permuted ownership
    const int i     = i0 + wv;                  // this wave's query row

    // A-frags: q rows i0 + l16 (16 distinct), dims quad*8..+7 and +32
    // (f16, pre-scaled by 1/sqrt(DH))
    const ushort* qp = qf + ((bS + i0 + l16) * cQH + h) * cDH + quad * 8;
    const half8 a0h = __builtin_bit_cast(half8, *(const uint4*)qp);
    const half8 a1h = __builtin_bit_cast(half8, *(const uint4*)(qp + 32));

    unsigned key[cNB];
    #pragma unroll
    for (int jb = 0; jb < cNB; ++jb) key[jb] = 0u;

    const int nk16   = it + 1;                      // 16-key blocks needed
    const int nchunk = (nk16 + 31) >> 5;            // 512-key chunks

    #pragma unroll
    for (int c = 0; c < 4; ++c) {
        if (c >= nchunk) break;                 // block-uniform branch
        // this wave's two 16-key blocks in the chunk
        #pragma unroll
        for (int half = 0; half < 2; ++half) {
            const int kb16 = (c << 5) + (half << 4) + wv;
            if (kb16 < nk16) {
                const ushort* kp = kf + ((bS + (kb16 << 4) + l16) * cKVH + kvh) * cDH + quad * 8;
                const uint4 b0 = *(const uint4*)kp;
                const uint4 b1 = *(const uint4*)(kp + 32);
                floatx4 acc = (floatx4){0.f, 0.f, 0.f, 0.f};
                acc = __builtin_amdgcn_mfma_f32_16x16x32_f16(
                    a0h, __builtin_bit_cast(half8, b0), acc, 0, 0, 0);
                acc = __builtin_amdgcn_mfma_f32_16x16x32_f16(
                    a1h, __builtin_bit_cast(half8, b1), acc, 0, 0, 0);
                // D: row = quad*4 + r2 (16 distinct q rows), col = l16.
                // fmap + causal mask folded into the store.
                const int jg  = (kb16 << 4) + l16;      // global key idx
                const int col = ((half << 4) + wv) * 16 + l16;  // col in chunk
                unsigned* sp = stg + (c & 1) * (cTI * cSTR) + col;
                #pragma unroll
                for (int r2 = 0; r2 < 4; ++r2) {
                    const int qrow = quad * 4 + r2;     // 0..15
                    sp[qrow * cSTR] = (jg <= i0 + qrow) ? fmap(acc[r2]) : 0u;
                }
            }
        }
        __syncthreads();
        // gather my row's 512 chunk keys at jperm positions (2-way banks)
        {
            const unsigned* rp = stg + (c & 1) * (cTI * cSTR) + wv * cSTR;
            #pragma unroll
            for (int jj = 0; jj < 8; ++jj) {
                const int j = (c << 9) + (jj << 6) + jperm;
                const unsigned kr = rp[(jj << 6) + jperm];
                key[(c << 3) + jj] = (j <= i) ? kr : 0u;
            }
        }
        // double buffer: next chunk stores to the other half; its barrier
        // orders those stores after this chunk's reads.
    }
    __syncthreads();   // staging dead; kl/jl lists may now clobber it

    // ---- Phase 2: per-row exact top-k + softmax + PV (1 row per wave) -----
    const int nb = (i >> 6) + 1;
    unsigned* kl = klA + wv * cLSZ;
    int*      jl = jlA + wv * cLSZ;
    const int vbase0 = (int)(((unsigned)bS * cKVH + kvh) * cDH);

    // row max + min over valid keys (valid keys are never 0)
    unsigned um = 0u, un = 0xFFFFFFFFu;
    #pragma unroll
    for (int jb = 0; jb < cNB; ++jb) {
        if (jb >= nb) break;
        const unsigned kk = key[jb];
        um = max(um, kk);
        un = min(un, kk ? kk : 0xFFFFFFFFu);
    }
    #pragma unroll
    for (int off = 32; off >= 1; off >>= 1) {
        um = max(um, (unsigned)__shfl_xor((int)um, off));
        un = min(un, (unsigned)__shfl_xor((int)un, off));
    }
    const float mrow = funmap(um);

    // exact 128th-largest key: bisection in [un, um] with exact-count early
    // exit; rows with i < 128 keep everything.
    unsigned ustar;
    if (i < cTOPK) {
        ustar = un;
    } else {
        unsigned lo = un, hi = um;
        while (lo < hi) {
            const unsigned d   = hi - lo;
            const unsigned mid = lo + (d >> 1) + (d & 1u);
            int cnt2 = 0;
            #pragma unroll
            for (int jb = 0; jb < cNB; ++jb) {
                if (jb >= nb) break;
                cnt2 += __popcll(__ballot(key[jb] >= mid));
            }
            if (cnt2 == cTOPK) {
                unsigned mn = 0xFFFFFFFFu;
                #pragma unroll
                for (int jb = 0; jb < cNB; ++jb) {
                    if (jb >= nb) break;
                    const unsigned kk = key[jb];
                    mn = min(mn, (kk >= mid) ? kk : 0xFFFFFFFFu);
                }
                #pragma unroll
                for (int off = 32; off >= 1; off >>= 1)
                    mn = min(mn, (unsigned)__shfl_xor((int)mn, off));
                lo = mn;
                break;
            }
            if (cnt2 > cTOPK) lo = mid; else hi = mid - 1u;
        }
        ustar = lo;
    }

    // ballot-prefix compaction of kept (j, key) into LDS
    const unsigned long long mlt = (1ull << lane) - 1ull;
    int base = 0;
    #pragma unroll
    for (int jb = 0; jb < cNB; ++jb) {
        if (jb >= nb) break;
        const int j = (jb << 6) + jperm;
        const bool keep = (j <= i) && (key[jb] >= ustar);
        const unsigned long long mk = __ballot(keep);
        const int pos = base + __popcll(mk & mlt);
        if (keep && pos < cLSZ) {
            kl[pos] = key[jb];
            jl[pos] = vbase0 + j * (cKVH * cDH);   // v element offset
        }
        base += __popcll(mk);
    }
    const int cnt = min(base, cLSZ);

    // weights + Z
    float zp = 0.f;
    for (int t = lane; t < cnt; t += 64) {
        const float s  = funmap(kl[t]);
        const float wt = __expf(s - mrow);
        ((float*)kl)[t] = wt;
        zp += wt;
    }
    #pragma unroll
    for (int off = 32; off >= 1; off >>= 1) zp += __shfl_xor(zp, off);
    const float invZ = 1.0f / zp;

    // PV: lane = d, f16 v, 8 independent accumulator chains, unroll 2 so
    // 16 v-loads issue per body (R12-proven load overlap).
    float ac0 = 0.f, ac1 = 0.f, ac2 = 0.f, ac3 = 0.f;
    float ac4 = 0.f, ac5 = 0.f, ac6 = 0.f, ac7 = 0.f;
    int t = 0;
    #pragma unroll 2
    for (; t + 7 < cnt; t += 8) {
        const float wt0 = ((float*)kl)[t];
        const float wt1 = ((float*)kl)[t + 1];
        const float wt2 = ((float*)kl)[t + 2];
        const float wt3 = ((float*)kl)[t + 3];
        const float wt4 = ((float*)kl)[t + 4];
        const float wt5 = ((float*)kl)[t + 5];
        const float wt6 = ((float*)kl)[t + 6];
        const float wt7 = ((float*)kl)[t + 7];
        const int vo0 = jl[t];
        const int vo1 = jl[t + 1];
        const int vo2 = jl[t + 2];
        const int vo3 = jl[t + 3];
        const int vo4 = jl[t + 4];
        const int vo5 = jl[t + 5];
        const int vo6 = jl[t + 6];
        const int vo7 = jl[t + 7];
        ac0 += wt0 * (float)__builtin_bit_cast(_Float16, vf[vo0 + lane]);
        ac1 += wt1 * (float)__builtin_bit_cast(_Float16, vf[vo1 + lane]);
        ac2 += wt2 * (float)__builtin_bit_cast(_Float16, vf[vo2 + lane]);
        ac3 += wt3 * (float)__builtin_bit_cast(_Float16, vf[vo3 + lane]);
        ac4 += wt4 * (float)__builtin_bit_cast(_Float16, vf[vo4 + lane]);
        ac5 += wt5 * (float)__builtin_bit_cast(_Float16, vf[vo5 + lane]);
        ac6 += wt6 * (float)__builtin_bit_cast(_Float16, vf[vo6 + lane]);
        ac7 += wt7 * (float)__builtin_bit_cast(_Float16, vf[vo7 + lane]);
    }
    for (; t < cnt; ++t) {
        const float wt = ((float*)kl)[t];
        const int   vo = jl[t];
        ac0 += wt * (float)__builtin_bit_cast(_Float16, vf[vo + lane]);
    }
    const float acc = ((ac0 + ac1) + (ac2 + ac3)) + ((ac4 + ac5) + (ac6 + ac7));
    out[((bS + i) * cQH + h) * cDH + lane] = f2bf(acc * invZ);
}

// ---------------------------------------------------------------------------
// Launch
// ---------------------------------------------------------------------------
extern "C" void kernel_launch(void* const* d_in, const int* in_sizes, int n_in,
                              void* d_out, int out_size, void* d_ws, size_t ws_size,
                              hipStream_t stream) {
    const float* x  = (const float*)d_in[0];
    const float* Wq = (const float*)d_in[1];
    const float* Wk = (const float*)d_in[2];
    const float* Wv = (const float*)d_in[3];
    const float* Wo = (const float*)d_in[4];
    float* out = (float*)d_out;

    // Workspace:
    //   bf16 inputs (contiguous, single merged cast): xh|Wqh|Wkh|Wvh|Woh
    //   abh : attention out (bf16); qff/kff roped f16; vff f16; trig table
    ushort* xh   = (ushort*)d_ws;
    ushort* Wqh  = xh  + (size_t)cM * cD;               // 1024 rows x 1024
    ushort* Wkh  = Wqh + (size_t)cNQ * cD;              // 256 rows
    ushort* Wvh  = Wkh + (size_t)cNK * cD;              // 256 rows (contig)
    ushort* Woh  = Wvh + (size_t)cNK * cD;              // 1024 rows
    ushort* abh  = Woh + (size_t)cD * cQH * cDH;        // 4M bf16 (attn out)
    ushort* qff  = abh + (size_t)cM * cQH * cDH;        // 4M f16 (roped q/8)
    ushort* kff  = qff + (size_t)cM * cQH * cDH;        // 1M f16 (roped k)
    ushort* vff  = kff + (size_t)cM * cKVH * cDH;       // 1M f16
    float*  ct   = (float*)(vff + (size_t)cM * cKVH * cDH);  // 64K f32
    float*  st   = ct + (size_t)cS * 32;                // 64K f32

    dim3 blk(256);

    // merged cast (all five bf16 GEMM inputs) + trig table, one launch
    cast_all_bf16_trig<<<(cCAST4 + cTRIG + 255) / 256, blk, 0, stream>>>(
        x, Wq, Wk, Wv, Wo, xh, ct, st);

    // ONE merged QKV projection with fused RoPE + f16 epilogue
    gemm_qkv_rope<<<dim3(cNQKV / 128, cM / 128), blk, 0, stream>>>(
        xh, Wqh, qff, kff, vff, ct, st);

    // Attention: cTI=16 / 1024 threads / 66 KB LDS (512-key chunks; kl/jl
    // lists alias staging) -> 2 blocks/CU; grid 4096, it descending.
    constexpr size_t aSMEM = (size_t)2 * cTI * cSTR * 4;    // 66048 B
    static_assert(cTI * cLSZ * 8 <= (int)aSMEM, "lists must fit in staging");
    attn_tile_kernel<<<dim3(32 * (cS / cTI)), dim3(1024), aSMEM, stream>>>(
        qff, kff, vff, abh);

    // Output projection (bf16 MFMA, fp32 out)
    gemm_bf16_bt<<<dim3(cD / 128, cM / 128), blk, 0, stream>>>(abh, Woh, out, cM, cD, cD);
}